// Round 3
// baseline (80.655 us; speedup 1.0000x reference)
//
#include <hip/hip_runtime.h>

// Inverse Haar wavelet transform: [B,H,W,4C] f32 -> [B,2H,2W,C] f32
// B=16, H=W=128, C4=256, n=64.
//
// out[b,2h  ,2w  ,c] = 0.5*(a1 - a2 - a3 + a4)
// out[b,2h  ,2w+1,c] = 0.5*(a1 + a2 - a3 - a4)
// out[b,2h+1,2w  ,c] = 0.5*(a1 - a2 + a3 - a4)
// out[b,2h+1,2w+1,c] = 0.5*(a1 + a2 + a3 + a4)
//
// One thread per (pixel, float4-of-channels). All loads/stores 16B/lane,
// full-cacheline coalesced.
//
// R3 experiment: output stores carry sc0+sc1+nt (system scope, nontemporal)
// to push the 268 MB/replay write stream past BOTH L2 and the memory-side
// Infinity Cache. The 256 MiB input then exactly fits the 256 MiB MALL and
// can stay resident across graph replays -> reads become L3 hits, kernel
// becomes write-BW-limited (~40-60 us) instead of R+W-limited (~80 us).

#define H 128
#define W 128
#define NPIX (16 * H * W)          // 262144 pixels
#define THREADS_TOTAL (NPIX * 16)  // 4194304

typedef float f4 __attribute__((ext_vector_type(4)));

__device__ __forceinline__ void stream_store(f4 v, f4* p) {
    asm volatile("global_store_dwordx4 %0, %1, off sc0 sc1 nt"
                 :: "v"(p), "v"(v)
                 : "memory");
}

__global__ __launch_bounds__(256) void iwt_kernel(
    const f4* __restrict__ in, f4* __restrict__ out) {
    int tid = blockIdx.x * blockDim.x + threadIdx.x;

    int c4  = tid & 15;   // which float4 within the 64 channels
    int pix = tid >> 4;   // b*H*W + h*W + w

    int w = pix & (W - 1);
    int h = (pix >> 7) & (H - 1);
    int b = pix >> 14;

    // Input pixel: 256 floats = 64 float4. Group g at float4-offset g*16 + c4.
    const f4* p = in + (size_t)pix * 64;
    f4 a1 = p[c4];
    f4 a2 = p[16 + c4];
    f4 a3 = p[32 + c4];
    f4 a4 = p[48 + c4];

    f4 ee = 0.5f * (a1 - a2 - a3 + a4);  // (2h,   2w)
    f4 eo = 0.5f * (a1 + a2 - a3 - a4);  // (2h,   2w+1)
    f4 oe = 0.5f * (a1 - a2 + a3 - a4);  // (2h+1, 2w)
    f4 oo = 0.5f * (a1 + a2 + a3 + a4);  // (2h+1, 2w+1)

    // Output: [B, 2H, 2W, 64] f32 = [B, 2H, 2W, 16] f4.
    size_t opix = ((size_t)b * (2 * H) + 2 * h) * (2 * W) + 2 * w;
    stream_store(ee, &out[(opix)             * 16 + c4]);
    stream_store(eo, &out[(opix + 1)         * 16 + c4]);
    stream_store(oe, &out[(opix + 2 * W)     * 16 + c4]);
    stream_store(oo, &out[(opix + 2 * W + 1) * 16 + c4]);
}

extern "C" void kernel_launch(void* const* d_in, const int* in_sizes, int n_in,
                              void* d_out, int out_size, void* d_ws, size_t ws_size,
                              hipStream_t stream) {
    const f4* in = (const f4*)d_in[0];
    f4* out = (f4*)d_out;
    const int block = 256;
    const int grid = THREADS_TOTAL / block;  // 16384
    iwt_kernel<<<grid, block, 0, stream>>>(in, out);
}